// Round 11
// baseline (989.195 us; speedup 1.0000x reference)
//
#include <hip/hip_runtime.h>
#include <hip/hip_cooperative_groups.h>

namespace cg = cooperative_groups;

#define NN 10000      // nodes
#define NNPAD 10112   // padded: 79*128
#define NE 160000     // edges
#define HF 512        // hidden/in features
#define LL 6          // layers
#define NC 64         // classes
#define KCAT (LL*HF)  // 3072
#define BN_EPS 1e-5f
#define FSPLIT 3      // final GEMM split-K chunks
#define AGG_SLOTS (((NN + 31) / 32) * 8)   // 2504
#define GEMM_TILES 316                      // 79 * 4
#define FIN_TILES (79 * FSPLIT)

typedef _Float16 f16x8 __attribute__((ext_vector_type(8)));
typedef _Float16 f16x4 __attribute__((ext_vector_type(4)));
typedef float f32x4 __attribute__((ext_vector_type(4)));

#define GLB(p) ((const __attribute__((address_space(1))) void*)(p))
#define LDSP(p) ((__attribute__((address_space(3))) void*)(p))

struct Params {
  const float* x; const float* W0; const float* Ws; const float* bs;
  const float* gamma; const float* beta; const float* rmean; const float* rvar;
  const float* linW; const float* linb; const int* src; const int* dst;
  float* out;
  _Float16* m_buf; _Float16* hcat; _Float16* zh; _Float16* wt; _Float16* lt;
  float* part; float* bnsc; float* bnsh; float* nsrc; float* ndst;
  unsigned* cnts; unsigned* roff; int* esrc;
};

// ==================== cooperative mono-kernel (all phases grid-stride) ====================
__launch_bounds__(256, 2)
__global__ void mono_kernel(Params p) {
  cg::grid_group grid = cg::this_grid();
  __shared__ __align__(16) char lds[32768];
  _Float16 (*As)[64] = reinterpret_cast<_Float16 (*)[64]>(lds);
  _Float16 (*Bs)[64] = reinterpret_cast<_Float16 (*)[64]>(lds + 16384);
  float (*t32)[33]   = reinterpret_cast<float (*)[33]>(lds);
  unsigned* wsum     = reinterpret_cast<unsigned*>(lds);

  const int tid  = threadIdx.x;
  const int bid  = blockIdx.x;
  const int nblk = gridDim.x;
  const int gsz  = nblk * 256;
  const int gtid = bid * 256 + tid;

  // ---- P0: zero counters | x->fp16 | W,lin transpose->fp16 ----
  for (int i = gtid; i < 3 * NN; i += gsz) p.cnts[i] = 0u;
  for (int i = gtid; i < NN * HF / 4; i += gsz) {
    float4 v = *(const float4*)&p.x[i * 4];
    f16x4 h; h.x = (_Float16)v.x; h.y = (_Float16)v.y; h.z = (_Float16)v.z; h.w = (_Float16)v.w;
    *(f16x4*)&p.zh[i * 4] = h;
  }
  {
    int tx = tid & 31, ty4 = (tid >> 5) * 4;
    for (int t = bid; t < 1536 + 192; t += nblk) {
      __syncthreads();
      if (t < 1536) {
        int l = t / 256, r = t % 256;
        int n0 = (r & 15) * 32, k0 = (r >> 4) * 32;
        const float* W = (l == 0) ? p.W0 : (p.Ws + (size_t)(l - 1) * HF * HF);
        #pragma unroll
        for (int j = 0; j < 4; ++j)
          t32[ty4 + j][tx] = W[(size_t)(k0 + ty4 + j) * HF + n0 + tx];
        __syncthreads();
        size_t base = (size_t)l * HF * HF;
        #pragma unroll
        for (int j = 0; j < 4; ++j)
          p.wt[base + (size_t)(n0 + ty4 + j) * HF + k0 + tx] = (_Float16)t32[tx][ty4 + j];
      } else {
        int r = t - 1536;
        int n0 = (r & 1) * 32, k0 = (r >> 1) * 32;
        #pragma unroll
        for (int j = 0; j < 4; ++j)
          t32[ty4 + j][tx] = p.linW[(size_t)(k0 + ty4 + j) * NC + n0 + tx];
        __syncthreads();
        #pragma unroll
        for (int j = 0; j < 4; ++j)
          p.lt[(size_t)(n0 + ty4 + j) * KCAT + k0 + tx] = (_Float16)t32[tx][ty4 + j];
      }
    }
  }
  grid.sync();

  // ---- P1: degree count ----
  for (int e = gtid; e < NE; e += gsz) {
    atomicAdd(&p.cnts[p.src[e]], 1u);
    atomicAdd(&p.cnts[NN + p.dst[e]], 1u);
  }
  grid.sync();

  // ---- P2: scan (block 0) | norms + BN prep (other blocks) ----
  if (bid == 0) {
    const unsigned* cnt = p.cnts + NN;
    int lane = tid & 63, wv = tid >> 6;
    unsigned base = 0;
    for (int c = 0; c < NN; c += 256) {
      int i = c + tid;
      unsigned v = (i < NN) ? cnt[i] : 0u;
      unsigned x = v;
      #pragma unroll
      for (int d = 1; d < 64; d <<= 1) {
        unsigned y = __shfl_up(x, d, 64);
        if (lane >= d) x += y;
      }
      if (lane == 63) wsum[wv] = x;
      __syncthreads();
      if (tid == 0) {
        unsigned s = 0;
        #pragma unroll
        for (int j = 0; j < 4; ++j) { s += wsum[j]; wsum[j] = s; }
      }
      __syncthreads();
      unsigned wbase = wv ? wsum[wv - 1] : 0u;
      if (i < NN) p.roff[i] = base + wbase + x - v;
      unsigned tot = wsum[3];
      __syncthreads();
      base += tot;
    }
    if (tid == 0) p.roff[NN] = base;
  } else {
    for (int i = (bid - 1) * 256 + tid; i < NN; i += (nblk - 1) * 256) {
      unsigned co = p.cnts[i];      if (co < 1u) co = 1u;
      unsigned ci = p.cnts[NN + i]; if (ci < 1u) ci = 1u;
      p.nsrc[i] = rsqrtf((float)co);
      p.ndst[i] = rsqrtf((float)ci);
      if (i < LL * HF) {
        float s = p.gamma[i] * rsqrtf(p.rvar[i] + BN_EPS);
        p.bnsc[i] = s;
        p.bnsh[i] = (p.bs[i] - p.rmean[i]) * s + p.beta[i];
      }
    }
  }
  grid.sync();

  // ---- P3: fill CSR ----
  for (int e = gtid; e < NE; e += gsz) {
    int d = p.dst[e];
    unsigned pos = atomicAdd(&p.cnts[2 * NN + d], 1u);
    p.esrc[p.roff[d] + pos] = p.src[e];
  }
  grid.sync();

  // ---- layers ----
  const int wid = tid >> 6, lane = tid & 63;
  const int wr = wid >> 1, wc = wid & 1;
  const int fr = lane & 15, kg = lane >> 4;
  const int rr = lane >> 3;
  const int ck = (lane & 7) ^ rr;

  for (int l = 0; l < LL; ++l) {
    const _Float16* __restrict__ Z = (l == 0) ? p.zh : (p.hcat + (size_t)(l - 1) * HF);
    int lda = (l == 0) ? HF : KCAT;
    const _Float16* __restrict__ Wt = p.wt + (size_t)l * HF * HF;

    // GEMM phase: 316 tiles of 128x128, grid-stride
    for (int t = bid; t < GEMM_TILES; t += nblk) {
      int m0 = (t >> 2) * 128;
      int n0 = (t & 3) * 128;
      f32x4 acc[4][4];
      #pragma unroll
      for (int m = 0; m < 4; ++m)
        #pragma unroll
        for (int n = 0; n < 4; ++n)
          acc[m][n] = (f32x4){0.f, 0.f, 0.f, 0.f};

      const _Float16* gA = Z  + (size_t)(m0 + wid * 32 + rr) * lda + ck * 8;
      const _Float16* gB = Wt + (size_t)(n0 + wid * 32 + rr) * HF + ck * 8;

      for (int k0 = 0; k0 < HF; k0 += 64) {
        __syncthreads();
        #pragma unroll
        for (int i = 0; i < 4; ++i) {
          __builtin_amdgcn_global_load_lds(GLB(gA + (size_t)i * 8 * lda + k0),
                                           LDSP(&As[wid * 32 + i * 8][0]), 16, 0, 0);
          __builtin_amdgcn_global_load_lds(GLB(gB + (size_t)i * 8 * HF + k0),
                                           LDSP(&Bs[wid * 32 + i * 8][0]), 16, 0, 0);
        }
        __syncthreads();
        #pragma unroll
        for (int kk = 0; kk < 2; ++kk) {
          f16x8 a[4], b[4];
          #pragma unroll
          for (int n = 0; n < 4; ++n) {
            int row = wc * 64 + n * 16 + fr;
            b[n] = *(const f16x8*)&Bs[row][((kk * 4 + kg) ^ (row & 7)) * 8];
          }
          #pragma unroll
          for (int m = 0; m < 4; ++m) {
            int row = wr * 64 + m * 16 + fr;
            a[m] = *(const f16x8*)&As[row][((kk * 4 + kg) ^ (row & 7)) * 8];
          }
          #pragma unroll
          for (int m = 0; m < 4; ++m)
            #pragma unroll
            for (int n = 0; n < 4; ++n)
              acc[m][n] = __builtin_amdgcn_mfma_f32_16x16x32_f16(a[m], b[n], acc[m][n], 0, 0, 0);
        }
      }
      #pragma unroll
      for (int m = 0; m < 4; ++m) {
        #pragma unroll
        for (int j = 0; j < 4; ++j) {
          int row = m0 + wr * 64 + m * 16 + kg * 4 + j;
          if (row < NN) {
            float s = p.nsrc[row];
            #pragma unroll
            for (int n = 0; n < 4; ++n) {
              int col = n0 + wc * 64 + n * 16 + fr;
              p.m_buf[(size_t)row * HF + col] = (_Float16)(acc[m][n][j] * s);
            }
          }
        }
      }
      __syncthreads();
    }
    grid.sync();

    // AGG phase: feature-chunked + XCD-pinned (nblk % 8 == 0 keeps b&7 fixed per block)
    {
      const float* __restrict__ bnsc = p.bnsc + l * HF;
      const float* __restrict__ bnsh = p.bnsh + l * HF;
      _Float16* __restrict__ hc = p.hcat + (size_t)l * HF;
      for (int b = bid; b < AGG_SLOTS; b += nblk) {
        int sl = b & 7, chunk = sl >> 1, grp = b >> 3;
        int wave = tid >> 6, sub = (tid >> 4) & 3;
        int n = grp * 32 + (sl & 1) * 16 + wave * 4 + sub;
        if (n < NN) {
          int f = chunk * 128 + (tid & 15) * 8;
          unsigned e0 = p.roff[n], e1 = p.roff[n + 1];
          float a0=0.f,a1=0.f,a2=0.f,a3=0.f,a4=0.f,a5=0.f,a6=0.f,a7=0.f;
          unsigned e = e0;
          for (; e + 4 <= e1; e += 4) {
            int es0 = p.esrc[e], es1 = p.esrc[e+1], es2 = p.esrc[e+2], es3 = p.esrc[e+3];
            f16x8 v0 = *(const f16x8*)&p.m_buf[(size_t)es0 * HF + f];
            f16x8 v1 = *(const f16x8*)&p.m_buf[(size_t)es1 * HF + f];
            f16x8 v2 = *(const f16x8*)&p.m_buf[(size_t)es2 * HF + f];
            f16x8 v3 = *(const f16x8*)&p.m_buf[(size_t)es3 * HF + f];
            a0 += (float)v0[0]+(float)v1[0]+(float)v2[0]+(float)v3[0];
            a1 += (float)v0[1]+(float)v1[1]+(float)v2[1]+(float)v3[1];
            a2 += (float)v0[2]+(float)v1[2]+(float)v2[2]+(float)v3[2];
            a3 += (float)v0[3]+(float)v1[3]+(float)v2[3]+(float)v3[3];
            a4 += (float)v0[4]+(float)v1[4]+(float)v2[4]+(float)v3[4];
            a5 += (float)v0[5]+(float)v1[5]+(float)v2[5]+(float)v3[5];
            a6 += (float)v0[6]+(float)v1[6]+(float)v2[6]+(float)v3[6];
            a7 += (float)v0[7]+(float)v1[7]+(float)v2[7]+(float)v3[7];
          }
          for (; e < e1; ++e) {
            int es = p.esrc[e];
            f16x8 v = *(const f16x8*)&p.m_buf[(size_t)es * HF + f];
            a0 += (float)v[0]; a1 += (float)v[1]; a2 += (float)v[2]; a3 += (float)v[3];
            a4 += (float)v[4]; a5 += (float)v[5]; a6 += (float)v[6]; a7 += (float)v[7];
          }
          float nd = p.ndst[n];
          float4 sc0 = *(const float4*)&bnsc[f];
          float4 sc1 = *(const float4*)&bnsc[f + 4];
          float4 sh0 = *(const float4*)&bnsh[f];
          float4 sh1 = *(const float4*)&bnsh[f + 4];
          float y0 = fmaxf(fmaf(a0 * nd, sc0.x, sh0.x), 0.f);
          float y1 = fmaxf(fmaf(a1 * nd, sc0.y, sh0.y), 0.f);
          float y2 = fmaxf(fmaf(a2 * nd, sc0.z, sh0.z), 0.f);
          float y3 = fmaxf(fmaf(a3 * nd, sc0.w, sh0.w), 0.f);
          float y4 = fmaxf(fmaf(a4 * nd, sc1.x, sh1.x), 0.f);
          float y5 = fmaxf(fmaf(a5 * nd, sc1.y, sh1.y), 0.f);
          float y6 = fmaxf(fmaf(a6 * nd, sc1.z, sh1.z), 0.f);
          float y7 = fmaxf(fmaf(a7 * nd, sc1.w, sh1.w), 0.f);
          f16x8 hv;
          hv[0]=(_Float16)y0; hv[1]=(_Float16)y1; hv[2]=(_Float16)y2; hv[3]=(_Float16)y3;
          hv[4]=(_Float16)y4; hv[5]=(_Float16)y5; hv[6]=(_Float16)y6; hv[7]=(_Float16)y7;
          *(f16x8*)&hc[(size_t)n * KCAT + f] = hv;
        }
      }
    }
    grid.sync();
  }

  // ---- final GEMM: 79 x FSPLIT tiles, grid-stride ----
  for (int t = bid; t < FIN_TILES; t += nblk) {
    int m0 = (t % 79) * 128;
    int sp = t / 79;
    int kbase = sp * (KCAT / FSPLIT);
    f32x4 acc[2][4];
    #pragma unroll
    for (int m = 0; m < 2; ++m)
      #pragma unroll
      for (int n = 0; n < 4; ++n)
        acc[m][n] = (f32x4){0.f, 0.f, 0.f, 0.f};

    const _Float16* gA = p.hcat + (size_t)(m0 + wid * 32 + rr) * KCAT + kbase + ck * 8;
    const _Float16* gB = p.lt   + (size_t)(wid * 16 + rr) * KCAT + kbase + ck * 8;

    for (int k0 = 0; k0 < KCAT / FSPLIT; k0 += 64) {
      __syncthreads();
      #pragma unroll
      for (int i = 0; i < 4; ++i)
        __builtin_amdgcn_global_load_lds(GLB(gA + (size_t)i * 8 * KCAT + k0),
                                         LDSP(&As[wid * 32 + i * 8][0]), 16, 0, 0);
      #pragma unroll
      for (int i = 0; i < 2; ++i)
        __builtin_amdgcn_global_load_lds(GLB(gB + (size_t)i * 8 * KCAT + k0),
                                         LDSP(&Bs[wid * 16 + i * 8][0]), 16, 0, 0);
      __syncthreads();
      #pragma unroll
      for (int kk = 0; kk < 2; ++kk) {
        f16x8 a[2], b[4];
        #pragma unroll
        for (int n = 0; n < 4; ++n) {
          int row = n * 16 + fr;
          b[n] = *(const f16x8*)&Bs[row][((kk * 4 + kg) ^ (row & 7)) * 8];
        }
        #pragma unroll
        for (int m = 0; m < 2; ++m) {
          int row = wid * 32 + m * 16 + fr;
          a[m] = *(const f16x8*)&As[row][((kk * 4 + kg) ^ (row & 7)) * 8];
        }
        #pragma unroll
        for (int m = 0; m < 2; ++m)
          #pragma unroll
          for (int n = 0; n < 4; ++n)
            acc[m][n] = __builtin_amdgcn_mfma_f32_16x16x32_f16(a[m], b[n], acc[m][n], 0, 0, 0);
      }
    }
    #pragma unroll
    for (int m = 0; m < 2; ++m) {
      #pragma unroll
      for (int j = 0; j < 4; ++j) {
        int row = m0 + wid * 32 + m * 16 + kg * 4 + j;
        if (row < NN) {
          #pragma unroll
          for (int n = 0; n < 4; ++n) {
            int col = n * 16 + fr;
            p.part[((size_t)sp * NN + row) * NC + col] = acc[m][n][j];
          }
        }
      }
    }
    __syncthreads();
  }
  grid.sync();

  // ---- final reduce + bias ----
  for (int i = gtid; i < NN * NC / 4; i += gsz) {
    int n = i >> 4, cq = i & 15;
    float4 s = *(const float4*)&p.linb[cq * 4];
    #pragma unroll
    for (int sp = 0; sp < FSPLIT; ++sp) {
      float4 v = *(const float4*)&p.part[((size_t)sp * NN + n) * NC + cq * 4];
      s.x += v.x; s.y += v.y; s.z += v.z; s.w += v.w;
    }
    *(float4*)&p.out[(size_t)n * NC + cq * 4] = s;
  }
}

// ==================== fallback multi-kernel path (r9, known-good) ====================

__global__ void zero_u32_kernel(unsigned* __restrict__ p, int n) {
  int i = blockIdx.x * blockDim.x + threadIdx.x;
  if (i < n) p[i] = 0u;
}

__global__ void deg_kernel(const int* __restrict__ src, const int* __restrict__ dst,
                           unsigned* __restrict__ cnt_out, unsigned* __restrict__ cnt_in) {
  int e = blockIdx.x * blockDim.x + threadIdx.x;
  if (e < NE) {
    atomicAdd(&cnt_out[src[e]], 1u);
    atomicAdd(&cnt_in[dst[e]], 1u);
  }
}

__global__ void prep_kernel(const unsigned* __restrict__ cnt_out, const unsigned* __restrict__ cnt_in,
                            float* __restrict__ norm_src, float* __restrict__ norm_dst,
                            const float* __restrict__ bs, const float* __restrict__ gamma,
                            const float* __restrict__ beta, const float* __restrict__ rmean,
                            const float* __restrict__ rvar,
                            float* __restrict__ scale, float* __restrict__ shift) {
  int i = blockIdx.x * blockDim.x + threadIdx.x;
  if (i < NN) {
    unsigned co = cnt_out[i]; if (co < 1u) co = 1u;
    unsigned ci = cnt_in[i];  if (ci < 1u) ci = 1u;
    norm_src[i] = rsqrtf((float)co);
    norm_dst[i] = rsqrtf((float)ci);
  }
  if (i < LL * HF) {
    float s = gamma[i] * rsqrtf(rvar[i] + BN_EPS);
    scale[i] = s;
    shift[i] = (bs[i] - rmean[i]) * s + beta[i];
  }
}

__global__ void scan_kernel(const unsigned* __restrict__ cnt, unsigned* __restrict__ off) {
  __shared__ unsigned wsum[16];
  int tid = threadIdx.x;
  int lane = tid & 63, wid = tid >> 6;
  unsigned base = 0;
  for (int c = 0; c < NN; c += 1024) {
    int i = c + tid;
    unsigned v = (i < NN) ? cnt[i] : 0u;
    unsigned x = v;
    #pragma unroll
    for (int d = 1; d < 64; d <<= 1) {
      unsigned y = __shfl_up(x, d, 64);
      if (lane >= d) x += y;
    }
    if (lane == 63) wsum[wid] = x;
    __syncthreads();
    if (wid == 0 && lane < 16) {
      unsigned s = wsum[lane];
      #pragma unroll
      for (int d = 1; d < 16; d <<= 1) {
        unsigned y = __shfl_up(s, d, 16);
        if (lane >= d) s += y;
      }
      wsum[lane] = s;
    }
    __syncthreads();
    unsigned wbase = wid ? wsum[wid - 1] : 0u;
    if (i < NN) off[i] = base + wbase + x - v;
    unsigned tot = wsum[15];
    __syncthreads();
    base += tot;
  }
  if (tid == 0) off[NN] = base;
}

__global__ void fill_kernel(const int* __restrict__ src, const int* __restrict__ dst,
                            const unsigned* __restrict__ off, unsigned* __restrict__ cursor,
                            int* __restrict__ edge_src) {
  int e = blockIdx.x * blockDim.x + threadIdx.x;
  if (e < NE) {
    int d = dst[e];
    unsigned p = atomicAdd(&cursor[d], 1u);
    edge_src[off[d] + p] = src[e];
  }
}

__global__ void convert_w(const float* __restrict__ W0, const float* __restrict__ Ws,
                          _Float16* __restrict__ Wt) {
  int l = blockIdx.z;
  const float* W = (l == 0) ? W0 : (Ws + (size_t)(l - 1) * HF * HF);
  __shared__ float t[32][33];
  int n0 = blockIdx.x * 32, k0 = blockIdx.y * 32;
  int tx = threadIdx.x & 31, ty4 = (threadIdx.x >> 5) * 4;
  #pragma unroll
  for (int j = 0; j < 4; ++j)
    t[ty4 + j][tx] = W[(size_t)(k0 + ty4 + j) * HF + n0 + tx];
  __syncthreads();
  size_t base = (size_t)l * HF * HF;
  #pragma unroll
  for (int j = 0; j < 4; ++j)
    Wt[base + (size_t)(n0 + ty4 + j) * HF + k0 + tx] = (_Float16)t[tx][ty4 + j];
}

__global__ void convert_lin(const float* __restrict__ linW, _Float16* __restrict__ Lt) {
  __shared__ float t[32][33];
  int n0 = blockIdx.x * 32, k0 = blockIdx.y * 32;
  int tx = threadIdx.x & 31, ty4 = (threadIdx.x >> 5) * 4;
  #pragma unroll
  for (int j = 0; j < 4; ++j)
    t[ty4 + j][tx] = linW[(size_t)(k0 + ty4 + j) * NC + n0 + tx];
  __syncthreads();
  #pragma unroll
  for (int j = 0; j < 4; ++j)
    Lt[(size_t)(n0 + ty4 + j) * KCAT + k0 + tx] = (_Float16)t[tx][ty4 + j];
}

__global__ void split_x(const float* __restrict__ x, _Float16* __restrict__ zh) {
  int i = blockIdx.x * blockDim.x + threadIdx.x;
  if (i >= NN * HF / 4) return;
  int base = i * 4;
  float4 v = *(const float4*)&x[base];
  f16x4 h;
  h.x = (_Float16)v.x; h.y = (_Float16)v.y; h.z = (_Float16)v.z; h.w = (_Float16)v.w;
  *(f16x4*)&zh[base] = h;
}

__launch_bounds__(256, 2)
__global__ void gemm_layer_f16(const _Float16* __restrict__ Z, int lda,
                               const _Float16* __restrict__ Wt,
                               const float* __restrict__ nsrc,
                               _Float16* __restrict__ Mout) {
  __shared__ _Float16 As[128][64];
  __shared__ _Float16 Bs[128][64];
  int m0 = blockIdx.y * 128;
  int n0 = blockIdx.x * 128;
  int wid = threadIdx.x >> 6, lane = threadIdx.x & 63;
  int wr = wid >> 1, wc = wid & 1;
  int fr = lane & 15, kg = lane >> 4;
  int rr = lane >> 3;
  int ck = (lane & 7) ^ rr;

  f32x4 acc[4][4];
  #pragma unroll
  for (int m = 0; m < 4; ++m)
    #pragma unroll
    for (int n = 0; n < 4; ++n)
      acc[m][n] = (f32x4){0.f, 0.f, 0.f, 0.f};

  const _Float16* gA = Z  + (size_t)(m0 + wid * 32 + rr) * lda + ck * 8;
  const _Float16* gB = Wt + (size_t)(n0 + wid * 32 + rr) * HF + ck * 8;

  for (int k0 = 0; k0 < HF; k0 += 64) {
    __syncthreads();
    #pragma unroll
    for (int i = 0; i < 4; ++i) {
      __builtin_amdgcn_global_load_lds(GLB(gA + (size_t)i * 8 * lda + k0),
                                       LDSP(&As[wid * 32 + i * 8][0]), 16, 0, 0);
      __builtin_amdgcn_global_load_lds(GLB(gB + (size_t)i * 8 * HF + k0),
                                       LDSP(&Bs[wid * 32 + i * 8][0]), 16, 0, 0);
    }
    __syncthreads();
    #pragma unroll
    for (int kk = 0; kk < 2; ++kk) {
      f16x8 a[4], b[4];
      #pragma unroll
      for (int n = 0; n < 4; ++n) {
        int row = wc * 64 + n * 16 + fr;
        b[n] = *(const f16x8*)&Bs[row][((kk * 4 + kg) ^ (row & 7)) * 8];
      }
      #pragma unroll
      for (int m = 0; m < 4; ++m) {
        int row = wr * 64 + m * 16 + fr;
        a[m] = *(const f16x8*)&As[row][((kk * 4 + kg) ^ (row & 7)) * 8];
      }
      #pragma unroll
      for (int m = 0; m < 4; ++m)
        #pragma unroll
        for (int n = 0; n < 4; ++n)
          acc[m][n] = __builtin_amdgcn_mfma_f32_16x16x32_f16(a[m], b[n], acc[m][n], 0, 0, 0);
    }
  }
  #pragma unroll
  for (int m = 0; m < 4; ++m) {
    #pragma unroll
    for (int j = 0; j < 4; ++j) {
      int row = m0 + wr * 64 + m * 16 + kg * 4 + j;
      if (row < NN) {
        float s = nsrc[row];
        #pragma unroll
        for (int n = 0; n < 4; ++n) {
          int col = n0 + wc * 64 + n * 16 + fr;
          Mout[(size_t)row * HF + col] = (_Float16)(acc[m][n][j] * s);
        }
      }
    }
  }
}

__launch_bounds__(256)
__global__ void agg_bn_kernel(const _Float16* __restrict__ Mm,
                              const int* __restrict__ edge_src,
                              const unsigned* __restrict__ row_off,
                              const float* __restrict__ norm_dst,
                              const float* __restrict__ bn_scale,
                              const float* __restrict__ bn_shift,
                              _Float16* __restrict__ hcat_col) {
  int s     = blockIdx.x & 7;
  int chunk = s >> 1;
  int grp   = blockIdx.x >> 3;
  int wave  = threadIdx.x >> 6;
  int sub   = (threadIdx.x >> 4) & 3;
  int n = grp * 32 + (s & 1) * 16 + wave * 4 + sub;
  if (n >= NN) return;
  int f = chunk * 128 + (threadIdx.x & 15) * 8;
  unsigned e0 = row_off[n], e1 = row_off[n + 1];
  float a0=0.f,a1=0.f,a2=0.f,a3=0.f,a4=0.f,a5=0.f,a6=0.f,a7=0.f;
  unsigned e = e0;
  for (; e + 4 <= e1; e += 4) {
    int s0 = edge_src[e], s1 = edge_src[e + 1], s2 = edge_src[e + 2], s3 = edge_src[e + 3];
    f16x8 v0 = *(const f16x8*)&Mm[(size_t)s0 * HF + f];
    f16x8 v1 = *(const f16x8*)&Mm[(size_t)s1 * HF + f];
    f16x8 v2 = *(const f16x8*)&Mm[(size_t)s2 * HF + f];
    f16x8 v3 = *(const f16x8*)&Mm[(size_t)s3 * HF + f];
    a0 += (float)v0[0]+(float)v1[0]+(float)v2[0]+(float)v3[0];
    a1 += (float)v0[1]+(float)v1[1]+(float)v2[1]+(float)v3[1];
    a2 += (float)v0[2]+(float)v1[2]+(float)v2[2]+(float)v3[2];
    a3 += (float)v0[3]+(float)v1[3]+(float)v2[3]+(float)v3[3];
    a4 += (float)v0[4]+(float)v1[4]+(float)v2[4]+(float)v3[4];
    a5 += (float)v0[5]+(float)v1[5]+(float)v2[5]+(float)v3[5];
    a6 += (float)v0[6]+(float)v1[6]+(float)v2[6]+(float)v3[6];
    a7 += (float)v0[7]+(float)v1[7]+(float)v2[7]+(float)v3[7];
  }
  for (; e < e1; ++e) {
    int sx = edge_src[e];
    f16x8 v = *(const f16x8*)&Mm[(size_t)sx * HF + f];
    a0 += (float)v[0]; a1 += (float)v[1]; a2 += (float)v[2]; a3 += (float)v[3];
    a4 += (float)v[4]; a5 += (float)v[5]; a6 += (float)v[6]; a7 += (float)v[7];
  }
  float nd = norm_dst[n];
  float4 s0 = *(const float4*)&bn_scale[f];
  float4 s1 = *(const float4*)&bn_scale[f + 4];
  float4 t0 = *(const float4*)&bn_shift[f];
  float4 t1 = *(const float4*)&bn_shift[f + 4];
  float y0 = fmaxf(fmaf(a0 * nd, s0.x, t0.x), 0.f);
  float y1 = fmaxf(fmaf(a1 * nd, s0.y, t0.y), 0.f);
  float y2 = fmaxf(fmaf(a2 * nd, s0.z, t0.z), 0.f);
  float y3 = fmaxf(fmaf(a3 * nd, s0.w, t0.w), 0.f);
  float y4 = fmaxf(fmaf(a4 * nd, s1.x, t1.x), 0.f);
  float y5 = fmaxf(fmaf(a5 * nd, s1.y, t1.y), 0.f);
  float y6 = fmaxf(fmaf(a6 * nd, s1.z, t1.z), 0.f);
  float y7 = fmaxf(fmaf(a7 * nd, s1.w, t1.w), 0.f);
  f16x8 hv;
  hv[0]=(_Float16)y0; hv[1]=(_Float16)y1; hv[2]=(_Float16)y2; hv[3]=(_Float16)y3;
  hv[4]=(_Float16)y4; hv[5]=(_Float16)y5; hv[6]=(_Float16)y6; hv[7]=(_Float16)y7;
  *(f16x8*)&hcat_col[(size_t)n * KCAT + f] = hv;
}

__launch_bounds__(256, 2)
__global__ void final_gemm_f16(const _Float16* __restrict__ Hc,
                               const _Float16* __restrict__ Lt,
                               float* __restrict__ part) {
  __shared__ _Float16 As[128][64];
  __shared__ _Float16 Bs[64][64];
  int m0 = blockIdx.x * 128;
  int sp = blockIdx.y;
  int kbase = sp * (KCAT / FSPLIT);
  int wid = threadIdx.x >> 6, lane = threadIdx.x & 63;
  int fr = lane & 15, kg = lane >> 4;
  int rr = lane >> 3;
  int ck = (lane & 7) ^ rr;

  f32x4 acc[2][4];
  #pragma unroll
  for (int m = 0; m < 2; ++m)
    #pragma unroll
    for (int n = 0; n < 4; ++n)
      acc[m][n] = (f32x4){0.f, 0.f, 0.f, 0.f};

  const _Float16* gA = Hc + (size_t)(m0 + wid * 32 + rr) * KCAT + kbase + ck * 8;
  const _Float16* gB = Lt + (size_t)(wid * 16 + rr) * KCAT + kbase + ck * 8;

  for (int k0 = 0; k0 < KCAT / FSPLIT; k0 += 64) {
    __syncthreads();
    #pragma unroll
    for (int i = 0; i < 4; ++i)
      __builtin_amdgcn_global_load_lds(GLB(gA + (size_t)i * 8 * KCAT + k0),
                                       LDSP(&As[wid * 32 + i * 8][0]), 16, 0, 0);
    #pragma unroll
    for (int i = 0; i < 2; ++i)
      __builtin_amdgcn_global_load_lds(GLB(gB + (size_t)i * 8 * KCAT + k0),
                                       LDSP(&Bs[wid * 16 + i * 8][0]), 16, 0, 0);
    __syncthreads();
    #pragma unroll
    for (int kk = 0; kk < 2; ++kk) {
      f16x8 a[2], b[4];
      #pragma unroll
      for (int n = 0; n < 4; ++n) {
        int row = n * 16 + fr;
        b[n] = *(const f16x8*)&Bs[row][((kk * 4 + kg) ^ (row & 7)) * 8];
      }
      #pragma unroll
      for (int m = 0; m < 2; ++m) {
        int row = wid * 32 + m * 16 + fr;
        a[m] = *(const f16x8*)&As[row][((kk * 4 + kg) ^ (row & 7)) * 8];
      }
      #pragma unroll
      for (int m = 0; m < 2; ++m)
        #pragma unroll
        for (int n = 0; n < 4; ++n)
          acc[m][n] = __builtin_amdgcn_mfma_f32_16x16x32_f16(a[m], b[n], acc[m][n], 0, 0, 0);
    }
  }
  #pragma unroll
  for (int m = 0; m < 2; ++m) {
    #pragma unroll
    for (int j = 0; j < 4; ++j) {
      int row = m0 + wid * 32 + m * 16 + kg * 4 + j;
      if (row < NN) {
        #pragma unroll
        for (int n = 0; n < 4; ++n) {
          int col = n * 16 + fr;
          part[((size_t)sp * NN + row) * NC + col] = acc[m][n][j];
        }
      }
    }
  }
}

__launch_bounds__(256)
__global__ void final_reduce(const float* __restrict__ part,
                             const float* __restrict__ linb,
                             float* __restrict__ out) {
  int i = blockIdx.x * blockDim.x + threadIdx.x;
  if (i >= NN * NC / 4) return;
  int n  = i >> 4;
  int cq = i & 15;
  float4 s = *(const float4*)&linb[cq * 4];
  #pragma unroll
  for (int sp = 0; sp < FSPLIT; ++sp) {
    float4 v = *(const float4*)&part[((size_t)sp * NN + n) * NC + cq * 4];
    s.x += v.x; s.y += v.y; s.z += v.z; s.w += v.w;
  }
  *(float4*)&out[(size_t)n * NC + cq * 4] = s;
}

// ==================== launch ====================

extern "C" void kernel_launch(void* const* d_in, const int* in_sizes, int n_in,
                              void* d_out, int out_size, void* d_ws, size_t ws_size,
                              hipStream_t stream) {
  char* w = (char*)d_ws;
  size_t o = 0;
  auto carve = [&](size_t bytes) -> void* {
    o = (o + 255) & ~(size_t)255;
    void* ptr = w + o;
    o += bytes;
    return ptr;
  };
  Params p;
  p.x     = (const float*)d_in[0];
  p.W0    = (const float*)d_in[1];
  p.Ws    = (const float*)d_in[2];
  p.bs    = (const float*)d_in[3];
  p.gamma = (const float*)d_in[4];
  p.beta  = (const float*)d_in[5];
  p.rmean = (const float*)d_in[6];
  p.rvar  = (const float*)d_in[7];
  p.linW  = (const float*)d_in[8];
  p.linb  = (const float*)d_in[9];
  p.src   = (const int*)d_in[10];
  p.dst   = (const int*)d_in[11];
  p.out   = (float*)d_out;

  p.m_buf = (_Float16*)carve((size_t)NNPAD * HF * 2);
  p.hcat  = (_Float16*)carve((size_t)NNPAD * KCAT * 2);
  p.zh    = (_Float16*)carve((size_t)NNPAD * HF * 2);
  p.wt    = (_Float16*)carve((size_t)LL * HF * HF * 2);
  p.lt    = (_Float16*)carve((size_t)NC * KCAT * 2);
  p.part  = (float*)carve((size_t)FSPLIT * NN * NC * 4);
  p.bnsc  = (float*)carve((size_t)LL * HF * 4);
  p.bnsh  = (float*)carve((size_t)LL * HF * 4);
  p.nsrc  = (float*)carve((size_t)NN * 4);
  p.ndst  = (float*)carve((size_t)NN * 4);
  p.cnts  = (unsigned*)carve((size_t)3 * NN * 4);
  p.roff  = (unsigned*)carve((size_t)(NN + 1) * 4);
  p.esrc  = (int*)carve((size_t)NE * 4);

  // --- try cooperative mono-kernel with runtime-derived grid ---
  bool coop_ok = false;
  int maxPerCU = 0, numCU = 0, dev = 0;
  hipError_t e1 = hipGetDevice(&dev);
  hipError_t e2 = hipDeviceGetAttribute(&numCU, hipDeviceAttributeMultiprocessorCount, dev);
  hipError_t e3 = hipOccupancyMaxActiveBlocksPerMultiprocessor(
      &maxPerCU, (const void*)mono_kernel, 256, 0);
  if (e1 == hipSuccess && e2 == hipSuccess && e3 == hipSuccess && maxPerCU > 0 && numCU > 0) {
    long grid = (long)maxPerCU * numCU;
    if (grid > 1024) grid = 1024;
    grid = (grid / 8) * 8;              // multiple of 8 for agg XCD pinning
    if (grid >= 8) {
      void* args[] = { &p };
      hipError_t el = hipLaunchCooperativeKernel((void*)mono_kernel,
                                                 dim3((unsigned)grid), dim3(256), args, 0, stream);
      coop_ok = (el == hipSuccess);
    }
  }
  if (coop_ok) return;

  // --- fallback: r9 multi-kernel sequence ---
  unsigned* cnt_out = p.cnts;
  unsigned* cnt_in  = p.cnts + NN;
  float* out = p.out;

  zero_u32_kernel<<<(3 * NN + 255) / 256, 256, 0, stream>>>(p.cnts, 3 * NN);
  deg_kernel<<<(NE + 255) / 256, 256, 0, stream>>>(p.src, p.dst, cnt_out, cnt_in);
  prep_kernel<<<(NN + 255) / 256, 256, 0, stream>>>(cnt_out, cnt_in, p.nsrc, p.ndst,
                                                    p.bs, p.gamma, p.beta, p.rmean, p.rvar,
                                                    p.bnsc, p.bnsh);
  scan_kernel<<<1, 1024, 0, stream>>>(cnt_in, p.roff);
  fill_kernel<<<(NE + 255) / 256, 256, 0, stream>>>(p.src, p.dst, p.roff, p.cnts + 2 * NN, p.esrc);
  convert_w<<<dim3(16, 16, 6), 256, 0, stream>>>(p.W0, p.Ws, p.wt);
  convert_lin<<<dim3(2, 96), 256, 0, stream>>>(p.linW, p.lt);
  split_x<<<(NN * HF / 4 + 255) / 256, 256, 0, stream>>>(p.x, p.zh);

  for (int l = 0; l < LL; ++l) {
    const _Float16* A   = (l == 0) ? p.zh : (p.hcat + (size_t)(l - 1) * HF);
    int             lda = (l == 0) ? HF : KCAT;
    gemm_layer_f16<<<dim3(HF / 128, NNPAD / 128), 256, 0, stream>>>(
        A, lda, p.wt + (size_t)l * HF * HF, p.nsrc, p.m_buf);
    agg_bn_kernel<<<AGG_SLOTS, 256, 0, stream>>>(p.m_buf, p.esrc, p.roff, p.ndst,
                                                 p.bnsc + l * HF, p.bnsh + l * HF,
                                                 p.hcat + (size_t)l * HF);
  }
  final_gemm_f16<<<dim3(NNPAD / 128, FSPLIT), 256, 0, stream>>>(p.hcat, p.lt, p.part);
  final_reduce<<<(NN * NC / 4 + 255) / 256, 256, 0, stream>>>(p.part, p.linb, out);
}

// Round 12
// 281.925 us; speedup vs baseline: 3.5087x; 3.5087x over previous
//
#include <hip/hip_runtime.h>

#define NN 10000      // nodes
#define NNPAD 10112   // padded: 79*128
#define NE 160000     // edges
#define HF 512        // hidden/in features
#define LL 6          // layers
#define NC 64         // classes
#define KCAT (LL*HF)  // 3072
#define BN_EPS 1e-5f
#define FSPLIT 3      // final GEMM split-K chunks
#define AGG_SLOTS (((NN + 31) / 32) * 8)   // 2504

typedef _Float16 f16x8 __attribute__((ext_vector_type(8)));
typedef _Float16 f16x4 __attribute__((ext_vector_type(4)));
typedef float f32x4 __attribute__((ext_vector_type(4)));

#define GLB(p) ((const __attribute__((address_space(1))) void*)(p))
#define LDSP(p) ((__attribute__((address_space(3))) void*)(p))

// ---------------- deg ----------------
__global__ void deg_kernel(const int* __restrict__ src, const int* __restrict__ dst,
                           unsigned* __restrict__ cnt_out, unsigned* __restrict__ cnt_in) {
  int e = blockIdx.x * blockDim.x + threadIdx.x;
  if (e < NE) {
    atomicAdd(&cnt_out[src[e]], 1u);
    atomicAdd(&cnt_in[dst[e]], 1u);
  }
}

// ---------------- fused setup: W transpose | lin transpose | x->fp16 | norms+BN ----------------
// blocks [0,1536): convert W tiles; [1536,1728): convert lin tiles;
// [1728,6728): split_x; [6728,6768): prep norms + BN scale/shift.
__global__ void fused_setup(const float* __restrict__ W0, const float* __restrict__ Ws,
                            const float* __restrict__ linW, const float* __restrict__ x,
                            const unsigned* __restrict__ cnt_out, const unsigned* __restrict__ cnt_in,
                            const float* __restrict__ bs, const float* __restrict__ gamma,
                            const float* __restrict__ beta, const float* __restrict__ rmean,
                            const float* __restrict__ rvar,
                            _Float16* __restrict__ Wt, _Float16* __restrict__ Lt,
                            _Float16* __restrict__ zh,
                            float* __restrict__ norm_src, float* __restrict__ norm_dst,
                            float* __restrict__ bnsc, float* __restrict__ bnsh) {
  __shared__ float t32[32][33];
  int b = blockIdx.x;
  int tid = threadIdx.x;
  if (b < 1536) {                 // W[k][n] -> Wt[n][k] fp16, 32x32 tiles
    int l = b >> 8, r = b & 255;
    int n0 = (r & 15) * 32, k0 = (r >> 4) * 32;
    const float* W = (l == 0) ? W0 : (Ws + (size_t)(l - 1) * HF * HF);
    int tx = tid & 31, ty4 = (tid >> 5) * 4;
    #pragma unroll
    for (int j = 0; j < 4; ++j)
      t32[ty4 + j][tx] = W[(size_t)(k0 + ty4 + j) * HF + n0 + tx];
    __syncthreads();
    size_t base = (size_t)l * HF * HF;
    #pragma unroll
    for (int j = 0; j < 4; ++j)
      Wt[base + (size_t)(n0 + ty4 + j) * HF + k0 + tx] = (_Float16)t32[tx][ty4 + j];
  } else if (b < 1728) {          // linW[k][c] -> Lt[c][k] fp16
    int r = b - 1536;
    int n0 = (r & 1) * 32, k0 = (r >> 1) * 32;
    int tx = tid & 31, ty4 = (tid >> 5) * 4;
    #pragma unroll
    for (int j = 0; j < 4; ++j)
      t32[ty4 + j][tx] = linW[(size_t)(k0 + ty4 + j) * NC + n0 + tx];
    __syncthreads();
    #pragma unroll
    for (int j = 0; j < 4; ++j)
      Lt[(size_t)(n0 + ty4 + j) * KCAT + k0 + tx] = (_Float16)t32[tx][ty4 + j];
  } else if (b < 6728) {          // x -> fp16
    int i = (b - 1728) * 256 + tid;       // float4 index
    if (i < NN * HF / 4) {
      float4 v = *(const float4*)&x[i * 4];
      f16x4 h;
      h.x = (_Float16)v.x; h.y = (_Float16)v.y; h.z = (_Float16)v.z; h.w = (_Float16)v.w;
      *(f16x4*)&zh[i * 4] = h;
    }
  } else {                        // norms + BN prep
    int i = (b - 6728) * 256 + tid;
    if (i < NN) {
      unsigned co = cnt_out[i]; if (co < 1u) co = 1u;
      unsigned ci = cnt_in[i];  if (ci < 1u) ci = 1u;
      norm_src[i] = rsqrtf((float)co);
      norm_dst[i] = rsqrtf((float)ci);
    }
    if (i < LL * HF) {
      float s = gamma[i] * rsqrtf(rvar[i] + BN_EPS);
      bnsc[i] = s;
      bnsh[i] = (bs[i] - rmean[i]) * s + beta[i];
    }
  }
}

// ---------------- scan: 256 threads x 40 serial nodes + wave scan of partials ----------------
__global__ void scan_kernel(const unsigned* __restrict__ cnt, unsigned* __restrict__ off) {
  __shared__ unsigned wsum[4];
  const int T = 40;               // 256*40 = 10240 >= NN
  int tid = threadIdx.x;
  int lane = tid & 63, wv = tid >> 6;
  int start = tid * T;
  unsigned s = 0;
  for (int j = 0; j < T; ++j) {
    int i = start + j;
    if (i < NN) s += cnt[i];
  }
  unsigned x = s;
  #pragma unroll
  for (int d = 1; d < 64; d <<= 1) {
    unsigned y = __shfl_up(x, d, 64);
    if (lane >= d) x += y;
  }
  if (lane == 63) wsum[wv] = x;
  __syncthreads();
  if (tid == 0) {
    unsigned acc = 0;
    #pragma unroll
    for (int j = 0; j < 4; ++j) { acc += wsum[j]; wsum[j] = acc; }
  }
  __syncthreads();
  unsigned run = (wv ? wsum[wv - 1] : 0u) + x - s;   // exclusive base for this thread
  for (int j = 0; j < T; ++j) {
    int i = start + j;
    if (i < NN) { off[i] = run; run += cnt[i]; }
  }
  if (tid == 0) off[NN] = wsum[3];
}

__global__ void fill_kernel(const int* __restrict__ src, const int* __restrict__ dst,
                            const unsigned* __restrict__ off, unsigned* __restrict__ cursor,
                            int* __restrict__ edge_src) {
  int e = blockIdx.x * blockDim.x + threadIdx.x;
  if (e < NE) {
    int d = dst[e];
    unsigned p = atomicAdd(&cursor[d], 1u);
    edge_src[off[d] + p] = src[e];
  }
}

// ---------------- layer GEMM via MFMA: Mout = ns ⊙ (Z @ Wt^T) (r9-proven) ----------------
__launch_bounds__(256, 2)
__global__ void gemm_layer_f16(const _Float16* __restrict__ Z, int lda,
                               const _Float16* __restrict__ Wt,
                               const float* __restrict__ nsrc,
                               _Float16* __restrict__ Mout) {
  __shared__ _Float16 As[128][64];
  __shared__ _Float16 Bs[128][64];
  int m0 = blockIdx.y * 128;
  int n0 = blockIdx.x * 128;
  int wid = threadIdx.x >> 6, lane = threadIdx.x & 63;
  int wr = wid >> 1, wc = wid & 1;
  int fr = lane & 15, kg = lane >> 4;
  int rr = lane >> 3;
  int ck = (lane & 7) ^ rr;

  f32x4 acc[4][4];
  #pragma unroll
  for (int m = 0; m < 4; ++m)
    #pragma unroll
    for (int n = 0; n < 4; ++n)
      acc[m][n] = (f32x4){0.f, 0.f, 0.f, 0.f};

  const _Float16* gA = Z  + (size_t)(m0 + wid * 32 + rr) * lda + ck * 8;
  const _Float16* gB = Wt + (size_t)(n0 + wid * 32 + rr) * HF + ck * 8;

  for (int k0 = 0; k0 < HF; k0 += 64) {
    __syncthreads();
    #pragma unroll
    for (int i = 0; i < 4; ++i) {
      __builtin_amdgcn_global_load_lds(GLB(gA + (size_t)i * 8 * lda + k0),
                                       LDSP(&As[wid * 32 + i * 8][0]), 16, 0, 0);
      __builtin_amdgcn_global_load_lds(GLB(gB + (size_t)i * 8 * HF + k0),
                                       LDSP(&Bs[wid * 32 + i * 8][0]), 16, 0, 0);
    }
    __syncthreads();
    #pragma unroll
    for (int kk = 0; kk < 2; ++kk) {
      f16x8 a[4], b[4];
      #pragma unroll
      for (int n = 0; n < 4; ++n) {
        int row = wc * 64 + n * 16 + fr;
        b[n] = *(const f16x8*)&Bs[row][((kk * 4 + kg) ^ (row & 7)) * 8];
      }
      #pragma unroll
      for (int m = 0; m < 4; ++m) {
        int row = wr * 64 + m * 16 + fr;
        a[m] = *(const f16x8*)&As[row][((kk * 4 + kg) ^ (row & 7)) * 8];
      }
      #pragma unroll
      for (int m = 0; m < 4; ++m)
        #pragma unroll
        for (int n = 0; n < 4; ++n)
          acc[m][n] = __builtin_amdgcn_mfma_f32_16x16x32_f16(a[m], b[n], acc[m][n], 0, 0, 0);
    }
  }
  #pragma unroll
  for (int m = 0; m < 4; ++m) {
    #pragma unroll
    for (int j = 0; j < 4; ++j) {
      int row = m0 + wr * 64 + m * 16 + kg * 4 + j;
      if (row < NN) {
        float s = nsrc[row];
        #pragma unroll
        for (int n = 0; n < 4; ++n) {
          int col = n0 + wc * 64 + n * 16 + fr;
          Mout[(size_t)row * HF + col] = (_Float16)(acc[m][n][j] * s);
        }
      }
    }
  }
}

// ---------------- aggregation, feature-chunked + XCD-pinned (r9-proven) ----------------
__launch_bounds__(256)
__global__ void agg_bn_kernel(const _Float16* __restrict__ Mm,
                              const int* __restrict__ edge_src,
                              const unsigned* __restrict__ row_off,
                              const float* __restrict__ norm_dst,
                              const float* __restrict__ bn_scale,
                              const float* __restrict__ bn_shift,
                              _Float16* __restrict__ hcat_col) {
  int s     = blockIdx.x & 7;
  int chunk = s >> 1;
  int grp   = blockIdx.x >> 3;
  int wave  = threadIdx.x >> 6;
  int sub   = (threadIdx.x >> 4) & 3;
  int n = grp * 32 + (s & 1) * 16 + wave * 4 + sub;
  if (n >= NN) return;
  int f = chunk * 128 + (threadIdx.x & 15) * 8;
  unsigned e0 = row_off[n], e1 = row_off[n + 1];
  float a0=0.f,a1=0.f,a2=0.f,a3=0.f,a4=0.f,a5=0.f,a6=0.f,a7=0.f;
  unsigned e = e0;
  for (; e + 4 <= e1; e += 4) {
    int s0 = edge_src[e], s1 = edge_src[e + 1], s2 = edge_src[e + 2], s3 = edge_src[e + 3];
    f16x8 v0 = *(const f16x8*)&Mm[(size_t)s0 * HF + f];
    f16x8 v1 = *(const f16x8*)&Mm[(size_t)s1 * HF + f];
    f16x8 v2 = *(const f16x8*)&Mm[(size_t)s2 * HF + f];
    f16x8 v3 = *(const f16x8*)&Mm[(size_t)s3 * HF + f];
    a0 += (float)v0[0]+(float)v1[0]+(float)v2[0]+(float)v3[0];
    a1 += (float)v0[1]+(float)v1[1]+(float)v2[1]+(float)v3[1];
    a2 += (float)v0[2]+(float)v1[2]+(float)v2[2]+(float)v3[2];
    a3 += (float)v0[3]+(float)v1[3]+(float)v2[3]+(float)v3[3];
    a4 += (float)v0[4]+(float)v1[4]+(float)v2[4]+(float)v3[4];
    a5 += (float)v0[5]+(float)v1[5]+(float)v2[5]+(float)v3[5];
    a6 += (float)v0[6]+(float)v1[6]+(float)v2[6]+(float)v3[6];
    a7 += (float)v0[7]+(float)v1[7]+(float)v2[7]+(float)v3[7];
  }
  for (; e < e1; ++e) {
    int sx = edge_src[e];
    f16x8 v = *(const f16x8*)&Mm[(size_t)sx * HF + f];
    a0 += (float)v[0]; a1 += (float)v[1]; a2 += (float)v[2]; a3 += (float)v[3];
    a4 += (float)v[4]; a5 += (float)v[5]; a6 += (float)v[6]; a7 += (float)v[7];
  }
  float nd = norm_dst[n];
  float4 s0 = *(const float4*)&bn_scale[f];
  float4 s1 = *(const float4*)&bn_scale[f + 4];
  float4 t0 = *(const float4*)&bn_shift[f];
  float4 t1 = *(const float4*)&bn_shift[f + 4];
  float y0 = fmaxf(fmaf(a0 * nd, s0.x, t0.x), 0.f);
  float y1 = fmaxf(fmaf(a1 * nd, s0.y, t0.y), 0.f);
  float y2 = fmaxf(fmaf(a2 * nd, s0.z, t0.z), 0.f);
  float y3 = fmaxf(fmaf(a3 * nd, s0.w, t0.w), 0.f);
  float y4 = fmaxf(fmaf(a4 * nd, s1.x, t1.x), 0.f);
  float y5 = fmaxf(fmaf(a5 * nd, s1.y, t1.y), 0.f);
  float y6 = fmaxf(fmaf(a6 * nd, s1.z, t1.z), 0.f);
  float y7 = fmaxf(fmaf(a7 * nd, s1.w, t1.w), 0.f);
  f16x8 hv;
  hv[0]=(_Float16)y0; hv[1]=(_Float16)y1; hv[2]=(_Float16)y2; hv[3]=(_Float16)y3;
  hv[4]=(_Float16)y4; hv[5]=(_Float16)y5; hv[6]=(_Float16)y6; hv[7]=(_Float16)y7;
  *(f16x8*)&hcat_col[(size_t)n * KCAT + f] = hv;
}

// ---------------- final GEMM, split-K over 3 chunks (r9-proven) ----------------
__launch_bounds__(256, 2)
__global__ void final_gemm_f16(const _Float16* __restrict__ Hc,
                               const _Float16* __restrict__ Lt,
                               float* __restrict__ part) {
  __shared__ _Float16 As[128][64];
  __shared__ _Float16 Bs[64][64];
  int m0 = blockIdx.x * 128;
  int sp = blockIdx.y;
  int kbase = sp * (KCAT / FSPLIT);
  int wid = threadIdx.x >> 6, lane = threadIdx.x & 63;
  int fr = lane & 15, kg = lane >> 4;
  int rr = lane >> 3;
  int ck = (lane & 7) ^ rr;

  f32x4 acc[2][4];
  #pragma unroll
  for (int m = 0; m < 2; ++m)
    #pragma unroll
    for (int n = 0; n < 4; ++n)
      acc[m][n] = (f32x4){0.f, 0.f, 0.f, 0.f};

  const _Float16* gA = Hc + (size_t)(m0 + wid * 32 + rr) * KCAT + kbase + ck * 8;
  const _Float16* gB = Lt + (size_t)(wid * 16 + rr) * KCAT + kbase + ck * 8;

  for (int k0 = 0; k0 < KCAT / FSPLIT; k0 += 64) {
    __syncthreads();
    #pragma unroll
    for (int i = 0; i < 4; ++i)
      __builtin_amdgcn_global_load_lds(GLB(gA + (size_t)i * 8 * KCAT + k0),
                                       LDSP(&As[wid * 32 + i * 8][0]), 16, 0, 0);
    #pragma unroll
    for (int i = 0; i < 2; ++i)
      __builtin_amdgcn_global_load_lds(GLB(gB + (size_t)i * 8 * KCAT + k0),
                                       LDSP(&Bs[wid * 16 + i * 8][0]), 16, 0, 0);
    __syncthreads();
    #pragma unroll
    for (int kk = 0; kk < 2; ++kk) {
      f16x8 a[2], b[4];
      #pragma unroll
      for (int n = 0; n < 4; ++n) {
        int row = n * 16 + fr;
        b[n] = *(const f16x8*)&Bs[row][((kk * 4 + kg) ^ (row & 7)) * 8];
      }
      #pragma unroll
      for (int m = 0; m < 2; ++m) {
        int row = wid * 32 + m * 16 + fr;
        a[m] = *(const f16x8*)&As[row][((kk * 4 + kg) ^ (row & 7)) * 8];
      }
      #pragma unroll
      for (int m = 0; m < 2; ++m)
        #pragma unroll
        for (int n = 0; n < 4; ++n)
          acc[m][n] = __builtin_amdgcn_mfma_f32_16x16x32_f16(a[m], b[n], acc[m][n], 0, 0, 0);
    }
  }
  #pragma unroll
  for (int m = 0; m < 2; ++m) {
    #pragma unroll
    for (int j = 0; j < 4; ++j) {
      int row = m0 + wid * 32 + m * 16 + kg * 4 + j;
      if (row < NN) {
        #pragma unroll
        for (int n = 0; n < 4; ++n) {
          int col = n * 16 + fr;
          part[((size_t)sp * NN + row) * NC + col] = acc[m][n][j];
        }
      }
    }
  }
}

__launch_bounds__(256)
__global__ void final_reduce(const float* __restrict__ part,
                             const float* __restrict__ linb,
                             float* __restrict__ out) {
  int i = blockIdx.x * blockDim.x + threadIdx.x;
  if (i >= NN * NC / 4) return;
  int n  = i >> 4;
  int cq = i & 15;
  float4 s = *(const float4*)&linb[cq * 4];
  #pragma unroll
  for (int sp = 0; sp < FSPLIT; ++sp) {
    float4 v = *(const float4*)&part[((size_t)sp * NN + n) * NC + cq * 4];
    s.x += v.x; s.y += v.y; s.z += v.z; s.w += v.w;
  }
  *(float4*)&out[(size_t)n * NC + cq * 4] = s;
}

// ---------------- launch ----------------

extern "C" void kernel_launch(void* const* d_in, const int* in_sizes, int n_in,
                              void* d_out, int out_size, void* d_ws, size_t ws_size,
                              hipStream_t stream) {
  const float* x     = (const float*)d_in[0];
  const float* W0    = (const float*)d_in[1];
  const float* Ws    = (const float*)d_in[2];
  const float* bs    = (const float*)d_in[3];
  const float* gamma = (const float*)d_in[4];
  const float* beta  = (const float*)d_in[5];
  const float* rmean = (const float*)d_in[6];
  const float* rvar  = (const float*)d_in[7];
  const float* linW  = (const float*)d_in[8];
  const float* linb  = (const float*)d_in[9];
  const int*   src   = (const int*)d_in[10];
  const int*   dst   = (const int*)d_in[11];
  float* out = (float*)d_out;

  char* w = (char*)d_ws;
  size_t o = 0;
  auto carve = [&](size_t bytes) -> void* {
    o = (o + 255) & ~(size_t)255;
    void* p = w + o;
    o += bytes;
    return p;
  };
  _Float16*  m_buf = (_Float16*)carve((size_t)NNPAD * HF * 2);
  _Float16*  hcat  = (_Float16*)carve((size_t)NNPAD * KCAT * 2);
  _Float16*  zh    = (_Float16*)carve((size_t)NNPAD * HF * 2);
  _Float16*  wt    = (_Float16*)carve((size_t)LL * HF * HF * 2);
  _Float16*  lt    = (_Float16*)carve((size_t)NC * KCAT * 2);
  float*     part  = (float*)carve((size_t)FSPLIT * NN * NC * 4);
  float*     bnsc  = (float*)carve((size_t)LL * HF * 4);
  float*     bnsh  = (float*)carve((size_t)LL * HF * 4);
  float*     nsrc  = (float*)carve((size_t)NN * 4);
  float*     ndst  = (float*)carve((size_t)NN * 4);
  unsigned*  cnts  = (unsigned*)carve((size_t)3 * NN * 4);
  unsigned*  roff  = (unsigned*)carve((size_t)(NN + 1) * 4);
  int*       esrc  = (int*)carve((size_t)NE * 4);

  unsigned* cnt_out = cnts;
  unsigned* cnt_in  = cnts + NN;
  unsigned* cursor  = cnts + 2 * NN;

  hipMemsetAsync(cnts, 0, (size_t)3 * NN * 4, stream);
  deg_kernel<<<(NE + 255) / 256, 256, 0, stream>>>(src, dst, cnt_out, cnt_in);
  fused_setup<<<6768, 256, 0, stream>>>(W0, Ws, linW, x, cnt_out, cnt_in,
                                        bs, gamma, beta, rmean, rvar,
                                        wt, lt, zh, nsrc, ndst, bnsc, bnsh);
  scan_kernel<<<1, 256, 0, stream>>>(cnt_in, roff);
  fill_kernel<<<(NE + 255) / 256, 256, 0, stream>>>(src, dst, roff, cursor, esrc);

  for (int l = 0; l < LL; ++l) {
    const _Float16* A   = (l == 0) ? zh : (hcat + (size_t)(l - 1) * HF);
    int             lda = (l == 0) ? HF : KCAT;
    gemm_layer_f16<<<dim3(HF / 128, NNPAD / 128), 256, 0, stream>>>(
        A, lda, wt + (size_t)l * HF * HF, nsrc, m_buf);
    agg_bn_kernel<<<AGG_SLOTS, 256, 0, stream>>>(m_buf, esrc, roff, ndst,
                                                 bnsc + l * HF, bnsh + l * HF,
                                                 hcat + (size_t)l * HF);
  }
  final_gemm_f16<<<dim3(NNPAD / 128, FSPLIT), 256, 0, stream>>>(hcat, lt, part);
  final_reduce<<<(NN * NC / 4 + 255) / 256, 256, 0, stream>>>(part, linb, out);
}